// Round 2
// baseline (3826.229 us; speedup 1.0000x reference)
//
#include <hip/hip_runtime.h>

// SNN: T=200, B=256, IN=784, N=1024, OUT=10
// W_rec = -0.5*(ones - I) => prev@W_rec = -0.5*(S_b - prev[b,j])  (exact in
// fp32: all partial sums are multiples of 0.5 with |.| <= 512).
// net_in[t] = x_t @ W_in is time-independent => one big fp32 GEMM up front
// into d_out's hidden_spikes region, then an in-place spike scan.
//
// NUMERICS CONTRACT: dynamics are knife-edge (absmax 512 of 611 = one
// marginal spike-step flip vs BLAS summation order). The GEMM keeps a single
// ascending-k fmaf chain per output element — bit-identical across rounds.
// No MFMA/bf16, no split-K, no reassociation, true division in the scan.

#define TT 200
#define BB 256
#define KK 784
#define NN 1024
#define OO 10

// ---------------- Phase 1: net = X(51200x784) @ W(784x1024), fp32 ----------
// 128x128 tile, BK=16, 256 threads, 8x8 micro-tile (2x2 quadrants of 4x4).
// v3: LDS double-buffer, ONE lgkm-only barrier per tile, tile loop unrolled
// by 2 so the buffer parity is a compile-time constant.
//   - v2 lesson (counters): __launch_bounds__(256,4) set a 64-VGPR budget ->
//     the 64-float acc spilled to scratch (WRITE_SIZE 205MB->2.5GB). Use
//     (256,2): budget 256, allocator takes ~110, zero spill. Occupancy is
//     then LDS/VGPR-limited (~16 waves/CU) which is ample: 1024 FMAs per
//     barrier only needs ~4 waves/SIMD to cover issue+LDS latency.
//   - lgkm-only barrier (inline asm) instead of __syncthreads: global
//     prefetch loads stay in flight across tile boundaries; only ds_writes
//     are drained before s_barrier.
__global__ __launch_bounds__(256, 2)
void gemm_net(const float* __restrict__ X, const float* __restrict__ W,
              float* __restrict__ C) {
  __shared__ float As[2][16][128];   // [buf][k][m] (A staged transposed)
  __shared__ float Bs[2][16][128];   // [buf][k][n]

  const int tid = threadIdx.x;
  const int n0 = blockIdx.x * 128;
  const int m0 = blockIdx.y * 128;
  const int tx = tid & 15;             // cols tx*4, 64+tx*4
  const int ty = tid >> 4;             // rows ty*4, 64+ty*4
  const int arow = tid >> 1;           // 0..127
  const int ak   = (tid & 1) * 8;      // 0 or 8
  const int brow = tid >> 5;           // 0..7 (and +8)
  const int bc   = (tid & 31) * 4;     // 0..124

  const float* ap = X + (size_t)(m0 + arow) * KK + ak;
  const float* bp = W + (size_t)brow * NN + n0 + bc;

  // regs <- tile 0
  float4 a0 = *(const float4*)(ap);
  float4 a1 = *(const float4*)(ap + 4);
  float4 b0 = *(const float4*)(bp);
  float4 b1 = *(const float4*)(bp + 8 * NN);

#define STAGE(q)                                                            \
  do {                                                                      \
    As[q][ak + 0][arow] = a0.x;  /* bank=arow%32, 2-way (free) */           \
    As[q][ak + 1][arow] = a0.y;                                             \
    As[q][ak + 2][arow] = a0.z;                                             \
    As[q][ak + 3][arow] = a0.w;                                             \
    As[q][ak + 4][arow] = a1.x;                                             \
    As[q][ak + 5][arow] = a1.y;                                             \
    As[q][ak + 6][arow] = a1.z;                                             \
    As[q][ak + 7][arow] = a1.w;                                             \
    *(float4*)&Bs[q][brow][bc] = b0;     /* lane-consecutive: clean */      \
    *(float4*)&Bs[q][brow + 8][bc] = b1;                                    \
  } while (0)

#define ADVANCE_LOAD()                                                      \
  do {                                                                      \
    ap += 16;                                                               \
    bp += 16 * NN;                                                          \
    a0 = *(const float4*)(ap);                                              \
    a1 = *(const float4*)(ap + 4);                                          \
    b0 = *(const float4*)(bp);                                              \
    b1 = *(const float4*)(bp + 8 * NN);                                     \
  } while (0)

#define LGKM_BARRIER() \
  __asm__ volatile("s_waitcnt lgkmcnt(0)\n\ts_barrier" ::: "memory")

  float acc[2][2][4][4] = {};

  // per-buffer compute: 16 k-steps x 64 FMAs; ascending-k fmaf chain per elem
#define COMPUTE(q)                                                          \
  do {                                                                      \
    const float4(*Ac4)[32] = (const float4(*)[32])As[q];                    \
    const float4(*Bc4)[32] = (const float4(*)[32])Bs[q];                    \
    _Pragma("unroll") for (int k = 0; k < 16; ++k) {                        \
      float4 A0 = Ac4[k][ty];          /* broadcast (free) */               \
      float4 A1 = Ac4[k][16 + ty];                                          \
      float4 B0 = Bc4[k][tx];          /* 2-way (free) */                   \
      float4 B1 = Bc4[k][16 + tx];                                          \
      float av[2][4] = {{A0.x, A0.y, A0.z, A0.w},                           \
                        {A1.x, A1.y, A1.z, A1.w}};                          \
      float bv[2][4] = {{B0.x, B0.y, B0.z, B0.w},                           \
                        {B1.x, B1.y, B1.z, B1.w}};                          \
      _Pragma("unroll") for (int qi = 0; qi < 2; ++qi)                      \
      _Pragma("unroll") for (int qj = 0; qj < 2; ++qj)                      \
      _Pragma("unroll") for (int i = 0; i < 4; ++i)                         \
      _Pragma("unroll") for (int j = 0; j < 4; ++j)                         \
        acc[qi][qj][i][j] = fmaf(av[qi][i], bv[qj][j], acc[qi][qj][i][j]);  \
    }                                                                       \
  } while (0)

  // prologue: buf0 <- tile 0; regs <- tile 1
  STAGE(0);
  ADVANCE_LOAD();
  LGKM_BARRIER();   // buf0 visible; tile-1 loads in flight

  // 24 pairs cover tiles 0..47; tile 48 is the epilogue.
  // Invariant at pair p entry: buf0 = tile 2p (staged), regs = tile 2p+1.
  for (int p = 0; p < 24; ++p) {
    // ---- half A: compute tile 2p (buf0) ----
    STAGE(1);                       // regs(tile 2p+1) -> buf1
    ADVANCE_LOAD();                 // regs <- tile 2p+2 (always exists)
    COMPUTE(0);
    LGKM_BARRIER();                 // buf1 visible; everyone done with buf0

    // ---- half B: compute tile 2p+1 (buf1) ----
    STAGE(0);                       // regs(tile 2p+2) -> buf0
    if (p < 23) ADVANCE_LOAD();     // regs <- tile 2p+3 (last pair: none)
    COMPUTE(1);
    LGKM_BARRIER();                 // buf0 visible; everyone done with buf1
  }
  // ---- epilogue: tile 48 (buf0) ----
  COMPUTE(0);

#undef STAGE
#undef ADVANCE_LOAD
#undef LGKM_BARRIER
#undef COMPUTE

#pragma unroll
  for (int qi = 0; qi < 2; ++qi)
#pragma unroll
    for (int i = 0; i < 4; ++i) {
      const int r = m0 + qi * 64 + ty * 4 + i;
#pragma unroll
      for (int qj = 0; qj < 2; ++qj) {
        float4 v = {acc[qi][qj][i][0], acc[qi][qj][i][1],
                    acc[qi][qj][i][2], acc[qi][qj][i][3]};
        *(float4*)(C + (size_t)r * NN + n0 + qj * 64 + tx * 4) = v;
      }
    }
}

// ---------------- Phase 2: sequential scan, one block per batch row --------
// 1024 threads (1 neuron each, 16 waves). hid holds net on entry; overwritten
// in place with spikes. One lgkm-only barrier per step (inline asm) so the
// spike stores and depth-2 net prefetch stay in flight across the barrier —
// __syncthreads' implicit vmcnt(0) drain would serialize a global-latency
// round trip into every step.  (UNCHANGED this round.)
__global__ __launch_bounds__(1024)
void snn_scan(float* __restrict__ hid, const float* __restrict__ Wout,
              float* __restrict__ logits) {
  constexpr float V_REST = -65.0f, THRESH0 = -50.0f, TAU_M = 20.0f,
                  TAU_TH = 100.0f, BETA = 5.0f, DT = 1.0f;
  const int b = blockIdx.x;
  const int tid = threadIdx.x;
  const int wave = tid >> 6, lane = tid & 63;
  __shared__ float s_part[2][16];
  __shared__ float s_log[16][OO];

  float mp = V_REST, th = THRESH0, prev = 0.0f, cnt = 0.0f;
  float S = 0.0f;
  const size_t base = (size_t)b * NN + tid;
  const size_t STEP = (size_t)BB * NN;

  // depth-2 prefetch pipeline for net
  float netc = hid[base];                 // t = 0
  float netn = hid[STEP + base];          // t = 1

  for (int t = 0; t < TT; ++t) {
    float rec = -0.5f * (S - prev);       // exact closed-form prev@W_rec
    float nv = netc + rec;                // matches np elementwise add order
    float m = mp + (V_REST - mp) / TAU_M; // true division, as reference
    m = m + nv * DT;
    bool spk = (m >= th);
    float s = spk ? 1.0f : 0.0f;
    th = (th + BETA * s) - ((th - THRESH0) / TAU_TH) * DT; // old th both terms
    mp = spk ? V_REST : m;
    cnt += s;
    prev = s;
    hid[(size_t)t * STEP + base] = s;

    // rotate prefetch: issue t+2 now (independent of this step's results)
    float netf = 0.0f;
    if (t + 2 < TT) netf = hid[(size_t)(t + 2) * STEP + base];
    netc = netn;
    netn = netf;

    // row spike count: ballot+popcount per wave; parity-buffered partials;
    // lgkm-only barrier (global loads/stores NOT drained).
    unsigned long long bal = __ballot(spk);
    if (lane == 0) s_part[t & 1][wave] = (float)__popcll(bal);
    __asm__ volatile("s_waitcnt lgkmcnt(0)\n\ts_barrier" ::: "memory");
    const float* sp = s_part[t & 1];
    float4 p0 = *(const float4*)(sp + 0);
    float4 p1 = *(const float4*)(sp + 4);
    float4 p2 = *(const float4*)(sp + 8);
    float4 p3 = *(const float4*)(sp + 12);
    S = ((p0.x + p0.y) + (p0.z + p0.w)) + ((p1.x + p1.y) + (p1.z + p1.w)) +
        ((p2.x + p2.y) + (p2.z + p2.w)) + ((p3.x + p3.y) + (p3.z + p3.w));
  }

  // logits[b,o] = sum_j cnt[b,j] * Wout[j,o]
  float lg[OO];
#pragma unroll
  for (int o = 0; o < OO; ++o) lg[o] = cnt * Wout[(size_t)tid * OO + o];
#pragma unroll
  for (int o = 0; o < OO; ++o) {
    float v = lg[o];
#pragma unroll
    for (int d = 32; d > 0; d >>= 1) v += __shfl_down(v, d, 64);
    if (lane == 0) s_log[wave][o] = v;
  }
  __syncthreads();
  if (tid < OO) {
    float v = 0.0f;
#pragma unroll
    for (int w = 0; w < 16; ++w) v += s_log[w][tid];
    logits[(size_t)b * OO + tid] = v;
  }
}

extern "C" void kernel_launch(void* const* d_in, const int* in_sizes, int n_in,
                              void* d_out, int out_size, void* d_ws,
                              size_t ws_size, hipStream_t stream) {
  const float* X    = (const float*)d_in[0];  // input_spikes [200][256][784]
  const float* Win  = (const float*)d_in[1];  // [784][1024]
  // d_in[2] = W_rec — unused (exact closed form)
  const float* Wout = (const float*)d_in[3];  // [1024][10]

  float* logits = (float*)d_out;              // [256][10]
  float* hid    = (float*)d_out + BB * OO;    // [200][256][1024]

  dim3 g1(NN / 128, TT * BB / 128);           // 8 x 400 blocks
  gemm_net<<<g1, 256, 0, stream>>>(X, Win, hid);
  snn_scan<<<BB, 1024, 0, stream>>>(hid, Wout, logits);
}

// Round 3
// 1592.418 us; speedup vs baseline: 2.4028x; 2.4028x over previous
//
#include <hip/hip_runtime.h>

// SNN: T=200, B=256, IN=784, N=1024, OUT=10
// W_rec = -0.5*(ones - I) => prev@W_rec = -0.5*(S_b - prev[b,j])  (exact in
// fp32). net_in[t] = x_t @ W_in is time-independent => one fp32 GEMM up
// front into d_out's hidden_spikes region, then an in-place spike scan.
//
// NUMERICS CONTRACT: dynamics are knife-edge (absmax 512 of 611 = one
// marginal spike-step flip vs BLAS summation order). The GEMM keeps a single
// ascending-k fmaf chain per output element — bit-identical across rounds.
// No MFMA/bf16, no split-K, no reassociation, true division in the scan.
//
// v4 history: v2/v3 proved register-prefetch double-buffering always spills
// (64 acc + 16 frag + 16 prefetch > what regalloc will keep live). v4 uses
// __builtin_amdgcn_global_load_lds DMA staging: ZERO staging registers,
// ZERO staging VALU. Per tile per wave: 4 DMA issues (async) -> 1024 FMAs
// -> __syncthreads (its vmcnt(0) drain is free: loads had ~2048 cyc cover).
// A is stored row-major [128][16] (DMA needs lane-linear dest) with an XOR
// quad-swizzle applied on the GLOBAL SOURCE address (per-lane) and undone on
// the LDS read -> A fragment reads are bank-conflict-free.

#define TT 200
#define BB 256
#define KK 784
#define NN 1024
#define OO 10

__device__ __forceinline__ void gload_lds16(const float* g, float* l) {
  __builtin_amdgcn_global_load_lds(
      (const __attribute__((address_space(1))) void*)g,
      (__attribute__((address_space(3))) void*)l, 16, 0, 0);
}

// compile-time float4 component select (pure SSA, no array, no movs)
#define F4E(v, e) ((e) == 0 ? (v).x : (e) == 1 ? (v).y : (e) == 2 ? (v).z : (v).w)

// ---------------- Phase 1: net = X(51200x784) @ W(784x1024), fp32 ----------
// 128x128 tile, BK=16, 256 threads, 8x8 micro-tile (2x2 quadrants of 4x4).
__global__ __launch_bounds__(256)
void gemm_net(const float* __restrict__ X, const float* __restrict__ W,
              float* __restrict__ C) {
  __shared__ float As[2][128][16];   // [buf][m][k] (k-quads XOR-swizzled)
  __shared__ float Bs[2][16][128];   // [buf][k][n]

  const int tid  = threadIdx.x;
  const int lane = tid & 63;
  const int w    = tid >> 6;         // wave 0..3 (uniform per wave)
  const int n0 = blockIdx.x * 128;
  const int m0 = blockIdx.y * 128;
  const int tx = tid & 15;           // output cols tx*4, 64+tx*4
  const int ty = tid >> 4;           // output rows ty*4, 64+ty*4 (0..15)
  const int tyq = ty & 3;            // A-read swizzle factor = (m>>2)&3

  // ---- DMA source pointers (per-lane globals; LDS dest = uniform base +
  //      lane*16B, hardware-defined) ----
  // A tile = 128 rows x 16 k (8 KB) = 8 wave-chunks of 16 rows.
  //   wave w, chunk c: LDS rows w*32+c*16 .. +15; lane i -> row +(i>>2),
  //   stored quad (i&3). Stored quad (i&3) must hold GLOBAL quad
  //   (i&3) ^ ((row>>2)&3); (row>>2)&3 == (i>>4) here.
  const int aR0 = w * 32 + (lane >> 2);        // chunk 0 row
  const int aCq = ((lane & 3) ^ ((lane >> 4) & 3)) * 4;
  const float* aSrc0 = X + (size_t)(m0 + aR0) * KK + aCq;
  const float* aSrc1 = X + (size_t)(m0 + aR0 + 16) * KK + aCq;
  // B tile = 16 rows x 128 n (8 KB) = 8 wave-chunks of 2 rows.
  //   wave w, chunk c: rows w*4+c*2 .. +1; lane i -> row +(i>>5),
  //   col (i&31)*4. No swizzle needed (reads are 2-way/free).
  const int bR0 = w * 4 + (lane >> 5);
  const int bCol = (lane & 31) * 4;
  const float* bSrc0 = W + (size_t)bR0 * NN + n0 + bCol;
  const float* bSrc1 = W + (size_t)(bR0 + 2) * NN + n0 + bCol;

  const int wa = w * 32;             // uniform LDS row bases per wave
  const int wb = w * 4;

#define ISSUE(q)                                                          \
  do {                                                                    \
    gload_lds16(aSrc0, &As[q][wa][0]);                                    \
    gload_lds16(aSrc1, &As[q][wa + 16][0]);                               \
    gload_lds16(bSrc0, &Bs[q][wb][0]);                                    \
    gload_lds16(bSrc1, &Bs[q][wb + 2][0]);                                \
    aSrc0 += 16; aSrc1 += 16;                                             \
    bSrc0 += 16 * NN; bSrc1 += 16 * NN;                                   \
  } while (0)

  float acc[2][2][4][4] = {};

  // Per-tile compute: 16 k-steps, ascending-k fmaf chain per acc element
  // (kq outer 0..3, dk inner 0..3 => k = kq*4+dk strictly ascending).
#define COMPUTE(q)                                                        \
  do {                                                                    \
    _Pragma("unroll") for (int kq = 0; kq < 4; ++kq) {                    \
      float4 bq[4][2];                                                    \
      _Pragma("unroll") for (int dk = 0; dk < 4; ++dk) {                  \
        bq[dk][0] = *(const float4*)&Bs[q][kq * 4 + dk][tx * 4];          \
        bq[dk][1] = *(const float4*)&Bs[q][kq * 4 + dk][64 + tx * 4];     \
      }                                                                   \
      _Pragma("unroll") for (int qi = 0; qi < 2; ++qi) {                  \
        _Pragma("unroll") for (int i = 0; i < 4; ++i) {                   \
          const int m = qi * 64 + ty * 4 + i;                             \
          float4 a4 = *(const float4*)&As[q][m][(kq ^ tyq) * 4];          \
          _Pragma("unroll") for (int dk = 0; dk < 4; ++dk) {              \
            _Pragma("unroll") for (int qj = 0; qj < 2; ++qj) {            \
              acc[qi][qj][i][0] =                                         \
                  fmaf(F4E(a4, dk), bq[dk][qj].x, acc[qi][qj][i][0]);     \
              acc[qi][qj][i][1] =                                         \
                  fmaf(F4E(a4, dk), bq[dk][qj].y, acc[qi][qj][i][1]);     \
              acc[qi][qj][i][2] =                                         \
                  fmaf(F4E(a4, dk), bq[dk][qj].z, acc[qi][qj][i][2]);     \
              acc[qi][qj][i][3] =                                         \
                  fmaf(F4E(a4, dk), bq[dk][qj].w, acc[qi][qj][i][3]);     \
            }                                                             \
          }                                                               \
        }                                                                 \
      }                                                                   \
    }                                                                     \
  } while (0)

  // prologue: tile 0 -> buf0 (one exposed DMA latency, once per kernel)
  ISSUE(0);
  __syncthreads();                    // vmcnt(0) drain + barrier: buf0 ready

  // 49 tiles = 24 pairs + epilogue. Invariant: entering pair p, buf0 holds
  // tile 2p (staged & visible).
  for (int p = 0; p < 24; ++p) {
    ISSUE(1);                         // tile 2p+1 -> buf1 (async DMA)
    COMPUTE(0);                       // tile 2p   (~2048 cyc of cover)
    __syncthreads();                  // buf1 ready; all waves done with buf0
    ISSUE(0);                         // tile 2p+2 -> buf0 (async DMA)
    COMPUTE(1);                       // tile 2p+1
    __syncthreads();                  // buf0 ready; all waves done with buf1
  }
  COMPUTE(0);                         // tile 48

#undef ISSUE
#undef COMPUTE

#pragma unroll
  for (int qi = 0; qi < 2; ++qi)
#pragma unroll
    for (int i = 0; i < 4; ++i) {
      const int r = m0 + qi * 64 + ty * 4 + i;
#pragma unroll
      for (int qj = 0; qj < 2; ++qj) {
        float4 v = {acc[qi][qj][i][0], acc[qi][qj][i][1],
                    acc[qi][qj][i][2], acc[qi][qj][i][3]};
        *(float4*)(C + (size_t)r * NN + n0 + qj * 64 + tx * 4) = v;
      }
    }
}

// ---------------- Phase 2: sequential scan, one block per batch row --------
// 1024 threads (1 neuron each, 16 waves). hid holds net on entry; overwritten
// in place with spikes. One lgkm-only barrier per step (inline asm) so the
// spike stores and depth-2 net prefetch stay in flight across the barrier.
// (UNCHANGED.)
__global__ __launch_bounds__(1024)
void snn_scan(float* __restrict__ hid, const float* __restrict__ Wout,
              float* __restrict__ logits) {
  constexpr float V_REST = -65.0f, THRESH0 = -50.0f, TAU_M = 20.0f,
                  TAU_TH = 100.0f, BETA = 5.0f, DT = 1.0f;
  const int b = blockIdx.x;
  const int tid = threadIdx.x;
  const int wave = tid >> 6, lane = tid & 63;
  __shared__ float s_part[2][16];
  __shared__ float s_log[16][OO];

  float mp = V_REST, th = THRESH0, prev = 0.0f, cnt = 0.0f;
  float S = 0.0f;
  const size_t base = (size_t)b * NN + tid;
  const size_t STEP = (size_t)BB * NN;

  // depth-2 prefetch pipeline for net
  float netc = hid[base];                 // t = 0
  float netn = hid[STEP + base];          // t = 1

  for (int t = 0; t < TT; ++t) {
    float rec = -0.5f * (S - prev);       // exact closed-form prev@W_rec
    float nv = netc + rec;                // matches np elementwise add order
    float m = mp + (V_REST - mp) / TAU_M; // true division, as reference
    m = m + nv * DT;
    bool spk = (m >= th);
    float s = spk ? 1.0f : 0.0f;
    th = (th + BETA * s) - ((th - THRESH0) / TAU_TH) * DT; // old th both terms
    mp = spk ? V_REST : m;
    cnt += s;
    prev = s;
    hid[(size_t)t * STEP + base] = s;

    // rotate prefetch: issue t+2 now (independent of this step's results)
    float netf = 0.0f;
    if (t + 2 < TT) netf = hid[(size_t)(t + 2) * STEP + base];
    netc = netn;
    netn = netf;

    // row spike count: ballot+popcount per wave; parity-buffered partials;
    // lgkm-only barrier (global loads/stores NOT drained).
    unsigned long long bal = __ballot(spk);
    if (lane == 0) s_part[t & 1][wave] = (float)__popcll(bal);
    __asm__ volatile("s_waitcnt lgkmcnt(0)\n\ts_barrier" ::: "memory");
    const float* sp = s_part[t & 1];
    float4 p0 = *(const float4*)(sp + 0);
    float4 p1 = *(const float4*)(sp + 4);
    float4 p2 = *(const float4*)(sp + 8);
    float4 p3 = *(const float4*)(sp + 12);
    S = ((p0.x + p0.y) + (p0.z + p0.w)) + ((p1.x + p1.y) + (p1.z + p1.w)) +
        ((p2.x + p2.y) + (p2.z + p2.w)) + ((p3.x + p3.y) + (p3.z + p3.w));
  }

  // logits[b,o] = sum_j cnt[b,j] * Wout[j,o]
  float lg[OO];
#pragma unroll
  for (int o = 0; o < OO; ++o) lg[o] = cnt * Wout[(size_t)tid * OO + o];
#pragma unroll
  for (int o = 0; o < OO; ++o) {
    float v = lg[o];
#pragma unroll
    for (int d = 32; d > 0; d >>= 1) v += __shfl_down(v, d, 64);
    if (lane == 0) s_log[wave][o] = v;
  }
  __syncthreads();
  if (tid < OO) {
    float v = 0.0f;
#pragma unroll
    for (int w = 0; w < 16; ++w) v += s_log[w][tid];
    logits[(size_t)b * OO + tid] = v;
  }
}

extern "C" void kernel_launch(void* const* d_in, const int* in_sizes, int n_in,
                              void* d_out, int out_size, void* d_ws,
                              size_t ws_size, hipStream_t stream) {
  const float* X    = (const float*)d_in[0];  // input_spikes [200][256][784]
  const float* Win  = (const float*)d_in[1];  // [784][1024]
  // d_in[2] = W_rec — unused (exact closed form)
  const float* Wout = (const float*)d_in[3];  // [1024][10]

  float* logits = (float*)d_out;              // [256][10]
  float* hid    = (float*)d_out + BB * OO;    // [200][256][1024]

  dim3 g1(NN / 128, TT * BB / 128);           // 8 x 400 blocks
  gemm_net<<<g1, 256, 0, stream>>>(X, Win, hid);
  snn_scan<<<BB, 1024, 0, stream>>>(hid, Wout, logits);
}

// Round 4
// 1515.017 us; speedup vs baseline: 2.5255x; 1.0511x over previous
//
#include <hip/hip_runtime.h>

// SNN: T=200, B=256, IN=784, N=1024, OUT=10
// W_rec = -0.5*(ones - I) => prev@W_rec = -0.5*(S_b - prev[b,j])  (exact in
// fp32). net_in[t] = x_t @ W_in is time-independent => one fp32 GEMM up
// front into d_out's hidden_spikes region, then an in-place spike scan.
//
// NUMERICS CONTRACT: dynamics are knife-edge (absmax 512 of 611 = one
// marginal spike-step flip vs BLAS summation order). The GEMM keeps a single
// ascending-k fmaf chain per output element — bit-identical across rounds.
// No MFMA/bf16, no split-K, no reassociation, true division in the scan.
//
// v5 history:
//  v2/v3: register-prefetch double-buffer -> spills (scratch GBs). Dead end.
//  v4: global_load_lds DMA staging, 256 thr, 8x8 micro-tile: no spill, 0 bank
//      conflicts, but VGPR=136 (past the 128 occupancy cliff, m69) -> ~1
//      block/CU, VALUBusy 48%, 1343us.
//  v5: SAME structure, 512 thr x 4x8 micro-tile: acc 64->32 regs, live set
//      ~85 VGPR -> 2-3 blocks/CU, ds_read/DMA latency hidden by TLP.

#define TT 200
#define BB 256
#define KK 784
#define NN 1024
#define OO 10

__device__ __forceinline__ void gload_lds16(const float* g, float* l) {
  __builtin_amdgcn_global_load_lds(
      (const __attribute__((address_space(1))) void*)g,
      (__attribute__((address_space(3))) void*)l, 16, 0, 0);
}

// compile-time float4 component select (pure SSA, no array, no movs)
#define F4E(v, e) ((e) == 0 ? (v).x : (e) == 1 ? (v).y : (e) == 2 ? (v).z : (v).w)

// ---------------- Phase 1: net = X(51200x784) @ W(784x1024), fp32 ----------
// 128x128 tile, BK=16, 512 threads, 4x8 micro-tile (rows ty*4..+3, col
// quads tx*4 and 64+tx*4). DMA staging: 2 global_load_lds_dwordx4 per wave
// per tile (A 1KB chunk + B 1KB chunk). A stored [m][k] row-major with k-quad
// XOR swizzle applied on the GLOBAL source address (per-lane) and undone on
// the LDS read (both-sides involution) -> A fragment reads conflict-free.
__global__ __launch_bounds__(512)
void gemm_net(const float* __restrict__ X, const float* __restrict__ W,
              float* __restrict__ C) {
  __shared__ float As[2][128][16];   // [buf][m][k] (k-quads XOR-swizzled)
  __shared__ float Bs[2][16][128];   // [buf][k][n]

  const int tid  = threadIdx.x;
  const int lane = tid & 63;
  const int w    = tid >> 6;         // wave 0..7 (uniform per wave)
  const int n0 = blockIdx.x * 128;
  const int m0 = blockIdx.y * 128;
  const int tx = tid & 15;           // col quads tx*4, 64+tx*4
  const int ty = tid >> 4;           // row group 0..31 -> rows ty*4..+3
  const int tyq = ty & 3;            // A-read swizzle factor = (m>>2)&3

  // ---- DMA source pointers (per-lane global; LDS dest = uniform base +
  //      lane*16B, hardware-defined) ----
  // A tile 128x16 (8KB) = 8 wave-chunks of 16 rows. Wave w -> rows 16w..+15,
  // lane i -> row 16w+(i>>2), stored quad (i&3) which must hold GLOBAL quad
  // (i&3)^((row>>2)&3); (row>>2)&3 == (i>>4)&3 here (16w>>2 ≡ 0 mod 4).
  const int aRow = w * 16 + (lane >> 2);
  const int aCq  = ((lane & 3) ^ ((lane >> 4) & 3)) * 4;
  const float* aSrc = X + (size_t)(m0 + aRow) * KK + aCq;
  // B tile 16x128 (8KB) = 8 wave-chunks of 2 rows. Wave w -> rows 2w..2w+1,
  // lane i -> row 2w+(i>>5), col (i&31)*4. Linear, no swizzle (reads 2-way).
  const int bRow = w * 2 + (lane >> 5);
  const float* bSrc = W + (size_t)bRow * NN + n0 + (lane & 31) * 4;

  const int wa = w * 16;             // uniform LDS row bases per wave
  const int wb = w * 2;

#define ISSUE(q)                                                          \
  do {                                                                    \
    gload_lds16(aSrc, &As[q][wa][0]);                                     \
    gload_lds16(bSrc, &Bs[q][wb][0]);                                     \
    aSrc += 16;                                                           \
    bSrc += 16 * NN;                                                      \
  } while (0)

  float acc[2][4][4] = {};           // [qj][i][j] = C[ty*4+i][qj*64+tx*4+j]

  // Per-tile compute: 16 k-steps; per acc element the FMA order is
  // (kq outer asc, dk inner asc) = k strictly ascending. Bit-identical to
  // v0/v4 chains.
#define COMPUTE(q)                                                        \
  do {                                                                    \
    _Pragma("unroll") for (int kq = 0; kq < 4; ++kq) {                    \
      float4 aq0 = *(const float4*)&As[q][ty * 4 + 0][(kq ^ tyq) * 4];    \
      float4 aq1 = *(const float4*)&As[q][ty * 4 + 1][(kq ^ tyq) * 4];    \
      float4 aq2 = *(const float4*)&As[q][ty * 4 + 2][(kq ^ tyq) * 4];    \
      float4 aq3 = *(const float4*)&As[q][ty * 4 + 3][(kq ^ tyq) * 4];    \
      _Pragma("unroll") for (int dk = 0; dk < 4; ++dk) {                  \
        float4 b0 = *(const float4*)&Bs[q][kq * 4 + dk][tx * 4];          \
        float4 b1 = *(const float4*)&Bs[q][kq * 4 + dk][64 + tx * 4];     \
        _Pragma("unroll") for (int i = 0; i < 4; ++i) {                   \
          const float a = F4E(i == 0 ? aq0 : i == 1 ? aq1 : i == 2 ? aq2  \
                                                                  : aq3,  \
                              dk);                                        \
          acc[0][i][0] = fmaf(a, b0.x, acc[0][i][0]);                     \
          acc[0][i][1] = fmaf(a, b0.y, acc[0][i][1]);                     \
          acc[0][i][2] = fmaf(a, b0.z, acc[0][i][2]);                     \
          acc[0][i][3] = fmaf(a, b0.w, acc[0][i][3]);                     \
          acc[1][i][0] = fmaf(a, b1.x, acc[1][i][0]);                     \
          acc[1][i][1] = fmaf(a, b1.y, acc[1][i][1]);                     \
          acc[1][i][2] = fmaf(a, b1.z, acc[1][i][2]);                     \
          acc[1][i][3] = fmaf(a, b1.w, acc[1][i][3]);                     \
        }                                                                 \
      }                                                                   \
    }                                                                     \
  } while (0)

  // prologue: tile 0 -> buf0 (one exposed DMA latency, once per kernel)
  ISSUE(0);
  __syncthreads();                    // vmcnt(0) drain + barrier: buf0 ready

  // 49 tiles = 24 pairs + epilogue. Invariant: entering pair p, buf0 holds
  // tile 2p (staged & visible).
  for (int p = 0; p < 24; ++p) {
    ISSUE(1);                         // tile 2p+1 -> buf1 (async DMA)
    COMPUTE(0);                       // tile 2p   (~1024 cyc/wave of cover)
    __syncthreads();                  // buf1 ready; all waves done with buf0
    ISSUE(0);                         // tile 2p+2 -> buf0 (async DMA)
    COMPUTE(1);                       // tile 2p+1
    __syncthreads();                  // buf0 ready; all waves done with buf1
  }
  COMPUTE(0);                         // tile 48

#undef ISSUE
#undef COMPUTE

#pragma unroll
  for (int i = 0; i < 4; ++i) {
    const int r = m0 + ty * 4 + i;
    float4 v0 = {acc[0][i][0], acc[0][i][1], acc[0][i][2], acc[0][i][3]};
    float4 v1 = {acc[1][i][0], acc[1][i][1], acc[1][i][2], acc[1][i][3]};
    *(float4*)(C + (size_t)r * NN + n0 + tx * 4) = v0;
    *(float4*)(C + (size_t)r * NN + n0 + 64 + tx * 4) = v1;
  }
}

// ---------------- Phase 2: sequential scan, one block per batch row --------
// 1024 threads (1 neuron each, 16 waves). hid holds net on entry; overwritten
// in place with spikes. One lgkm-only barrier per step (inline asm) so the
// spike stores and depth-2 net prefetch stay in flight across the barrier.
// (UNCHANGED.)
__global__ __launch_bounds__(1024)
void snn_scan(float* __restrict__ hid, const float* __restrict__ Wout,
              float* __restrict__ logits) {
  constexpr float V_REST = -65.0f, THRESH0 = -50.0f, TAU_M = 20.0f,
                  TAU_TH = 100.0f, BETA = 5.0f, DT = 1.0f;
  const int b = blockIdx.x;
  const int tid = threadIdx.x;
  const int wave = tid >> 6, lane = tid & 63;
  __shared__ float s_part[2][16];
  __shared__ float s_log[16][OO];

  float mp = V_REST, th = THRESH0, prev = 0.0f, cnt = 0.0f;
  float S = 0.0f;
  const size_t base = (size_t)b * NN + tid;
  const size_t STEP = (size_t)BB * NN;

  // depth-2 prefetch pipeline for net
  float netc = hid[base];                 // t = 0
  float netn = hid[STEP + base];          // t = 1

  for (int t = 0; t < TT; ++t) {
    float rec = -0.5f * (S - prev);       // exact closed-form prev@W_rec
    float nv = netc + rec;                // matches np elementwise add order
    float m = mp + (V_REST - mp) / TAU_M; // true division, as reference
    m = m + nv * DT;
    bool spk = (m >= th);
    float s = spk ? 1.0f : 0.0f;
    th = (th + BETA * s) - ((th - THRESH0) / TAU_TH) * DT; // old th both terms
    mp = spk ? V_REST : m;
    cnt += s;
    prev = s;
    hid[(size_t)t * STEP + base] = s;

    // rotate prefetch: issue t+2 now (independent of this step's results)
    float netf = 0.0f;
    if (t + 2 < TT) netf = hid[(size_t)(t + 2) * STEP + base];
    netc = netn;
    netn = netf;

    // row spike count: ballot+popcount per wave; parity-buffered partials;
    // lgkm-only barrier (global loads/stores NOT drained).
    unsigned long long bal = __ballot(spk);
    if (lane == 0) s_part[t & 1][wave] = (float)__popcll(bal);
    __asm__ volatile("s_waitcnt lgkmcnt(0)\n\ts_barrier" ::: "memory");
    const float* sp = s_part[t & 1];
    float4 p0 = *(const float4*)(sp + 0);
    float4 p1 = *(const float4*)(sp + 4);
    float4 p2 = *(const float4*)(sp + 8);
    float4 p3 = *(const float4*)(sp + 12);
    S = ((p0.x + p0.y) + (p0.z + p0.w)) + ((p1.x + p1.y) + (p1.z + p1.w)) +
        ((p2.x + p2.y) + (p2.z + p2.w)) + ((p3.x + p3.y) + (p3.z + p3.w));
  }

  // logits[b,o] = sum_j cnt[b,j] * Wout[j,o]
  float lg[OO];
#pragma unroll
  for (int o = 0; o < OO; ++o) lg[o] = cnt * Wout[(size_t)tid * OO + o];
#pragma unroll
  for (int o = 0; o < OO; ++o) {
    float v = lg[o];
#pragma unroll
    for (int d = 32; d > 0; d >>= 1) v += __shfl_down(v, d, 64);
    if (lane == 0) s_log[wave][o] = v;
  }
  __syncthreads();
  if (tid < OO) {
    float v = 0.0f;
#pragma unroll
    for (int w = 0; w < 16; ++w) v += s_log[w][tid];
    logits[(size_t)b * OO + tid] = v;
  }
}

extern "C" void kernel_launch(void* const* d_in, const int* in_sizes, int n_in,
                              void* d_out, int out_size, void* d_ws,
                              size_t ws_size, hipStream_t stream) {
  const float* X    = (const float*)d_in[0];  // input_spikes [200][256][784]
  const float* Win  = (const float*)d_in[1];  // [784][1024]
  // d_in[2] = W_rec — unused (exact closed form)
  const float* Wout = (const float*)d_in[3];  // [1024][10]

  float* logits = (float*)d_out;              // [256][10]
  float* hid    = (float*)d_out + BB * OO;    // [200][256][1024]

  dim3 g1(NN / 128, TT * BB / 128);           // 8 x 400 blocks
  gemm_net<<<g1, 512, 0, stream>>>(X, Win, hid);
  snn_scan<<<BB, 1024, 0, stream>>>(hid, Wout, logits);
}

// Round 6
// 1349.730 us; speedup vs baseline: 2.8348x; 1.1225x over previous
//
#include <hip/hip_runtime.h>

// SNN: T=200, B=256, IN=784, N=1024, OUT=10
// W_rec = -0.5*(ones - I) => prev@W_rec = -0.5*(S_b - prev[b,j])  (exact in
// fp32). net_in[t] = x_t @ W_in is time-independent => one fp32 GEMM up
// front into d_out's hidden_spikes region, then an in-place spike scan.
//
// NUMERICS CONTRACT: dynamics are knife-edge (absmax 512 of 611 = one
// marginal spike-step flip vs BLAS summation order). The GEMM keeps a single
// ascending-k fmaf chain per output element — bit-identical across rounds.
// No MFMA/bf16, no split-K, no reassociation, true division in the scan.
//
// v6 history:
//  v2/v3: register-prefetch dbuf -> spills. Dead end.
//  v4: DMA staging, 256thr 8x8: no spill, 0 conflicts, but 136 VGPR -> 1
//      wave/SIMD (empirical law: waves/SIMD = floor(256/VGPR)) -> latency
//      exposed, VALUBusy 48%, 1343us.
//  v5: 512thr 4x8: 88 VGPR, 2 waves/SIMD, latency hidden — but 1.5 B/FMA of
//      LDS delivery vs the ~1.0 B/FMA balanced budget -> LDS wall at
//      VALUBusy ~52-58%, 1283us.
//  v6: 256thr 8x8 (1.0 B/FMA, the balanced shape) with the A fragment held
//      as b64 HALVES (16 regs instead of 32) and B streamed per k (8 regs):
//      live set ~105 <= 128 cap -> 2 waves/SIMD AND the 8x8 LDS ratio.
//  (round 5 bench was an infra failure — this is v6 resubmitted unchanged.)

#define TT 200
#define BB 256
#define KK 784
#define NN 1024
#define OO 10

__device__ __forceinline__ void gload_lds16(const float* g, float* l) {
  __builtin_amdgcn_global_load_lds(
      (const __attribute__((address_space(1))) void*)g,
      (__attribute__((address_space(3))) void*)l, 16, 0, 0);
}

// ---------------- Phase 1: net = X(51200x784) @ W(784x1024), fp32 ----------
// 128x128 tile, BK=16, 256 threads, 8x8 micro-tile (2x2 quadrants of 4x4).
// DMA staging (4 global_load_lds_dwordx4 per wave per tile). A stored [m][k]
// row-major with k-quad XOR swizzle applied on the GLOBAL source address
// (per-lane) and undone on the LDS read (both-sides involution) -> A reads
// conflict-free (4 distinct rows/wave spread across 16 banks).
__global__ __launch_bounds__(256, 2)
void gemm_net(const float* __restrict__ X, const float* __restrict__ W,
              float* __restrict__ C) {
  __shared__ float As[2][128][16];   // [buf][m][k] (k-quads XOR-swizzled)
  __shared__ float Bs[2][16][128];   // [buf][k][n]

  const int tid  = threadIdx.x;
  const int lane = tid & 63;
  const int w    = tid >> 6;         // wave 0..3 (uniform per wave)
  const int n0 = blockIdx.x * 128;
  const int m0 = blockIdx.y * 128;
  const int tx = tid & 15;           // output cols tx*4, 64+tx*4
  const int ty = tid >> 4;           // output rows ty*4..+3, 64+ty*4..+3
  const int tyq = ty & 3;            // A-read swizzle factor = (m>>2)&3

  // ---- DMA source pointers (per-lane global; LDS dest = uniform base +
  //      lane*16B, hardware-defined) ----
  // A tile 128x16 (8KB) = 8 wave-chunks of 16 rows. Wave w: LDS rows
  // w*32+c*16..+15 (c=0,1); lane i -> row +(i>>2), stored quad (i&3) which
  // holds GLOBAL quad (i&3)^((row>>2)&3) = (i&3)^((i>>4)&3).
  const int aR0 = w * 32 + (lane >> 2);
  const int aCq = ((lane & 3) ^ ((lane >> 4) & 3)) * 4;
  const float* aSrc0 = X + (size_t)(m0 + aR0) * KK + aCq;
  const float* aSrc1 = X + (size_t)(m0 + aR0 + 16) * KK + aCq;
  // B tile 16x128 (8KB) = 8 wave-chunks of 2 rows. Wave w: rows w*4+c*2;
  // lane i -> row +(i>>5), col (i&31)*4. Linear (reads are 2-way/free).
  const int bR0 = w * 4 + (lane >> 5);
  const int bCol = (lane & 31) * 4;
  const float* bSrc0 = W + (size_t)bR0 * NN + n0 + bCol;
  const float* bSrc1 = W + (size_t)(bR0 + 2) * NN + n0 + bCol;

  const int wa = w * 32;             // uniform LDS row bases per wave
  const int wb = w * 4;

#define ISSUE(q)                                                          \
  do {                                                                    \
    gload_lds16(aSrc0, &As[q][wa][0]);                                    \
    gload_lds16(aSrc1, &As[q][wa + 16][0]);                               \
    gload_lds16(bSrc0, &Bs[q][wb][0]);                                    \
    gload_lds16(bSrc1, &Bs[q][wb + 2][0]);                                \
    aSrc0 += 16; aSrc1 += 16;                                             \
    bSrc0 += 16 * NN; bSrc1 += 16 * NN;                                   \
  } while (0)

  float acc[2][2][4][4] = {};        // [qi][qj][i][j]

  // Per-tile compute: 16 k-steps. Per acc element the FMA order is
  // kq(0..3) -> h(0..1) -> d(0..1), i.e. k = kq*4+h*2+d strictly ascending:
  // bit-identical chain to v0/v4/v5. A fragment held as float2 halves
  // (16 regs live) so total live set stays under the 128-reg cap.
#define COMPUTE(q)                                                        \
  do {                                                                    \
    _Pragma("unroll") for (int kq = 0; kq < 4; ++kq) {                    \
      _Pragma("unroll") for (int h = 0; h < 2; ++h) {                     \
        float2 ah[8];                                                     \
        _Pragma("unroll") for (int i = 0; i < 4; ++i) {                   \
          ah[i] = *(const float2*)&As[q][ty * 4 + i][(kq ^ tyq) * 4 + h * 2]; \
          ah[4 + i] =                                                     \
              *(const float2*)&As[q][64 + ty * 4 + i][(kq ^ tyq) * 4 + h * 2];\
        }                                                                 \
        _Pragma("unroll") for (int d = 0; d < 2; ++d) {                   \
          const int kk = kq * 4 + h * 2 + d;                              \
          float4 b0 = *(const float4*)&Bs[q][kk][tx * 4];                 \
          float4 b1 = *(const float4*)&Bs[q][kk][64 + tx * 4];            \
          _Pragma("unroll") for (int qi = 0; qi < 2; ++qi) {              \
            _Pragma("unroll") for (int i = 0; i < 4; ++i) {               \
              const float a = (d == 0) ? ah[qi * 4 + i].x                 \
                                       : ah[qi * 4 + i].y;                \
              acc[qi][0][i][0] = fmaf(a, b0.x, acc[qi][0][i][0]);         \
              acc[qi][0][i][1] = fmaf(a, b0.y, acc[qi][0][i][1]);         \
              acc[qi][0][i][2] = fmaf(a, b0.z, acc[qi][0][i][2]);         \
              acc[qi][0][i][3] = fmaf(a, b0.w, acc[qi][0][i][3]);         \
              acc[qi][1][i][0] = fmaf(a, b1.x, acc[qi][1][i][0]);         \
              acc[qi][1][i][1] = fmaf(a, b1.y, acc[qi][1][i][1]);         \
              acc[qi][1][i][2] = fmaf(a, b1.z, acc[qi][1][i][2]);         \
              acc[qi][1][i][3] = fmaf(a, b1.w, acc[qi][1][i][3]);         \
            }                                                             \
          }                                                               \
        }                                                                 \
      }                                                                   \
    }                                                                     \
  } while (0)

  // prologue: tile 0 -> buf0 (one exposed DMA latency, once per kernel)
  ISSUE(0);
  __syncthreads();                    // vmcnt(0) drain + barrier: buf0 ready

  // 49 tiles = 24 pairs + epilogue. Invariant: entering pair p, buf0 holds
  // tile 2p (staged & visible).
  for (int p = 0; p < 24; ++p) {
    ISSUE(1);                         // tile 2p+1 -> buf1 (async DMA)
    COMPUTE(0);                       // tile 2p   (~2048 cyc of cover)
    __syncthreads();                  // buf1 ready; all waves done with buf0
    ISSUE(0);                         // tile 2p+2 -> buf0 (async DMA)
    COMPUTE(1);                       // tile 2p+1
    __syncthreads();                  // buf0 ready; all waves done with buf1
  }
  COMPUTE(0);                         // tile 48

#undef ISSUE
#undef COMPUTE

#pragma unroll
  for (int qi = 0; qi < 2; ++qi)
#pragma unroll
    for (int i = 0; i < 4; ++i) {
      const int r = m0 + qi * 64 + ty * 4 + i;
      float4 v0 = {acc[qi][0][i][0], acc[qi][0][i][1], acc[qi][0][i][2],
                   acc[qi][0][i][3]};
      float4 v1 = {acc[qi][1][i][0], acc[qi][1][i][1], acc[qi][1][i][2],
                   acc[qi][1][i][3]};
      *(float4*)(C + (size_t)r * NN + n0 + tx * 4) = v0;
      *(float4*)(C + (size_t)r * NN + n0 + 64 + tx * 4) = v1;
    }
}

// ---------------- Phase 2: sequential scan, one block per batch row --------
// 1024 threads (1 neuron each, 16 waves). hid holds net on entry; overwritten
// in place with spikes. One lgkm-only barrier per step (inline asm) so the
// spike stores and depth-2 net prefetch stay in flight across the barrier.
// (UNCHANGED.)
__global__ __launch_bounds__(1024)
void snn_scan(float* __restrict__ hid, const float* __restrict__ Wout,
              float* __restrict__ logits) {
  constexpr float V_REST = -65.0f, THRESH0 = -50.0f, TAU_M = 20.0f,
                  TAU_TH = 100.0f, BETA = 5.0f, DT = 1.0f;
  const int b = blockIdx.x;
  const int tid = threadIdx.x;
  const int wave = tid >> 6, lane = tid & 63;
  __shared__ float s_part[2][16];
  __shared__ float s_log[16][OO];

  float mp = V_REST, th = THRESH0, prev = 0.0f, cnt = 0.0f;
  float S = 0.0f;
  const size_t base = (size_t)b * NN + tid;
  const size_t STEP = (size_t)BB * NN;

  // depth-2 prefetch pipeline for net
  float netc = hid[base];                 // t = 0
  float netn = hid[STEP + base];          // t = 1

  for (int t = 0; t < TT; ++t) {
    float rec = -0.5f * (S - prev);       // exact closed-form prev@W_rec
    float nv = netc + rec;                // matches np elementwise add order
    float m = mp + (V_REST - mp) / TAU_M; // true division, as reference
    m = m + nv * DT;
    bool spk = (m >= th);
    float s = spk ? 1.0f : 0.0f;
    th = (th + BETA * s) - ((th - THRESH0) / TAU_TH) * DT; // old th both terms
    mp = spk ? V_REST : m;
    cnt += s;
    prev = s;
    hid[(size_t)t * STEP + base] = s;

    // rotate prefetch: issue t+2 now (independent of this step's results)
    float netf = 0.0f;
    if (t + 2 < TT) netf = hid[(size_t)(t + 2) * STEP + base];
    netc = netn;
    netn = netf;

    // row spike count: ballot+popcount per wave; parity-buffered partials;
    // lgkm-only barrier (global loads/stores NOT drained).
    unsigned long long bal = __ballot(spk);
    if (lane == 0) s_part[t & 1][wave] = (float)__popcll(bal);
    __asm__ volatile("s_waitcnt lgkmcnt(0)\n\ts_barrier" ::: "memory");
    const float* sp = s_part[t & 1];
    float4 p0 = *(const float4*)(sp + 0);
    float4 p1 = *(const float4*)(sp + 4);
    float4 p2 = *(const float4*)(sp + 8);
    float4 p3 = *(const float4*)(sp + 12);
    S = ((p0.x + p0.y) + (p0.z + p0.w)) + ((p1.x + p1.y) + (p1.z + p1.w)) +
        ((p2.x + p2.y) + (p2.z + p2.w)) + ((p3.x + p3.y) + (p3.z + p3.w));
  }

  // logits[b,o] = sum_j cnt[b,j] * Wout[j,o]
  float lg[OO];
#pragma unroll
  for (int o = 0; o < OO; ++o) lg[o] = cnt * Wout[(size_t)tid * OO + o];
#pragma unroll
  for (int o = 0; o < OO; ++o) {
    float v = lg[o];
#pragma unroll
    for (int d = 32; d > 0; d >>= 1) v += __shfl_down(v, d, 64);
    if (lane == 0) s_log[wave][o] = v;
  }
  __syncthreads();
  if (tid < OO) {
    float v = 0.0f;
#pragma unroll
    for (int w = 0; w < 16; ++w) v += s_log[w][tid];
    logits[(size_t)b * OO + tid] = v;
  }
}

extern "C" void kernel_launch(void* const* d_in, const int* in_sizes, int n_in,
                              void* d_out, int out_size, void* d_ws,
                              size_t ws_size, hipStream_t stream) {
  const float* X    = (const float*)d_in[0];  // input_spikes [200][256][784]
  const float* Win  = (const float*)d_in[1];  // [784][1024]
  // d_in[2] = W_rec — unused (exact closed form)
  const float* Wout = (const float*)d_in[3];  // [1024][10]

  float* logits = (float*)d_out;              // [256][10]
  float* hid    = (float*)d_out + BB * OO;    // [200][256][1024]

  dim3 g1(NN / 128, TT * BB / 128);           // 8 x 400 blocks
  gemm_net<<<g1, 256, 0, stream>>>(X, Win, hid);
  snn_scan<<<BB, 1024, 0, stream>>>(hid, Wout, logits);
}

// Round 7
// 1304.689 us; speedup vs baseline: 2.9327x; 1.0345x over previous
//
#include <hip/hip_runtime.h>

// SNN: T=200, B=256, IN=784, N=1024, OUT=10
// W_rec = -0.5*(ones - I) => prev@W_rec = -0.5*(S_b - prev[b,j])  (exact in
// fp32). net_in[t] = x_t @ W_in is time-independent => one fp32 GEMM up
// front into d_out's hidden_spikes region, then an in-place spike scan.
//
// NUMERICS CONTRACT: dynamics are knife-edge (absmax 512 of 611 = one
// marginal spike-step flip vs BLAS summation order). The GEMM keeps a single
// ascending-k fmaf chain per output element — bit-identical across rounds.
// No MFMA/bf16, no split-K, no reassociation, true division in the scan.
//
// v7 history (all counters-measured):
//  v0 (8x8, 80 VGPR, ~3 waves/SIMD): 950us, VALUBusy 75%. The 8x8 optimum.
//  v2/v3: register-prefetch dbuf -> always spills. Dead end.
//  v4 (DMA, 8x8, 136 VGPR -> 1 wave/SIMD): stall 700us, 1343us.
//  v5 (DMA, 4x8@512thr, 88 VGPR -> 2 waves): stall 616us, 1283us.
//  v6 (DMA, 8x8 b64-halves, 128 VGPR -> 2 waves, mild spill): 1107us.
//  LAW (fits all): waves/SIMD = floor(256/VGPR); busy ~660-710us in every
//  variant; the spread is pure stall, monotone DOWN in waves/SIMD.
//  v7: DMA + 4x8 micro (32 acc) on a 128x64 tile @256thr: live set ~70 VGPR
//  <= 85 cap from __launch_bounds__(256,3) -> 3 waves/SIMD AND near-zero
//  staging VALU. B re-reads (16 vs 8 n-blocks per X panel) are L3-absorbed.

#define TT 200
#define BB 256
#define KK 784
#define NN 1024
#define OO 10

__device__ __forceinline__ void gload_lds16(const float* g, float* l) {
  __builtin_amdgcn_global_load_lds(
      (const __attribute__((address_space(1))) void*)g,
      (__attribute__((address_space(3))) void*)l, 16, 0, 0);
}

// ---------------- Phase 1: net = X(51200x784) @ W(784x1024), fp32 ----------
// 128x64 tile, BK=16, 256 threads, 4x8 micro-tile (rows ty*4..+3, col quads
// tx*4 and 32+tx*4). DMA staging: 3 global_load_lds_dwordx4 per wave per
// tile (A 2x1KB + B 1x1KB). A stored [m][k] with k-quad XOR swizzle applied
// on the GLOBAL source address (per-lane) and undone on the LDS read
// (both-sides involution, verified bit-exact in v4/v6) -> A reads are 4
// distinct b64 addrs/wave on distinct banks + 16-lane broadcast: free.
// B reads: 8 distinct b128 spanning all 32 banks + 8-lane broadcast: free.
__global__ __launch_bounds__(256, 3)
void gemm_net(const float* __restrict__ X, const float* __restrict__ W,
              float* __restrict__ C) {
  __shared__ float As[2][128][16];   // [buf][m][k] (k-quads XOR-swizzled)
  __shared__ float Bs[2][16][64];    // [buf][k][n]

  const int tid  = threadIdx.x;
  const int lane = tid & 63;
  const int w    = tid >> 6;         // wave 0..3 (uniform per wave)
  const int n0 = blockIdx.x * 64;
  const int m0 = blockIdx.y * 128;
  const int tx = tid & 7;            // col quads tx*4, 32+tx*4
  const int ty = tid >> 3;           // row group 0..31 -> rows ty*4..+3
  const int tyq = ty & 3;            // A-read swizzle factor = (row>>2)&3
  const int ty4 = ty * 4, tx4 = tx * 4;

  // ---- DMA source pointers (per-lane global; LDS dest = uniform wave base
  //      + lane*16B, hardware-defined) ----
  // A tile 128x16 (8KB): wave w fills LDS rows w*32..+15 and w*32+16..+31.
  // Lane i -> row +(i>>2); stored quad (i&3) holds GLOBAL quad
  // (i&3)^((row>>2)&3) = (i&3)^((i>>4)&3)  (w*32>>2 is 0 mod 4).
  const int aR0 = w * 32 + (lane >> 2);
  const int aCq = ((lane & 3) ^ ((lane >> 4) & 3)) * 4;
  const float* aSrc0 = X + (size_t)(m0 + aR0) * KK + aCq;
  const float* aSrc1 = X + (size_t)(m0 + aR0 + 16) * KK + aCq;
  // B tile 16x64 (4KB): wave w fills rows w*4..+3. Lane i -> row +(i>>4),
  // col (i&15)*4 (16B contiguous in global). Linear, no swizzle.
  const int bR0 = w * 4 + (lane >> 4);
  const float* bSrc = W + (size_t)bR0 * NN + n0 + (lane & 15) * 4;

  const int wa = w * 32;             // uniform LDS row bases per wave
  const int wb = w * 4;

#define ISSUE(q)                                                          \
  do {                                                                    \
    gload_lds16(aSrc0, &As[q][wa][0]);                                    \
    gload_lds16(aSrc1, &As[q][wa + 16][0]);                               \
    gload_lds16(bSrc, &Bs[q][wb][0]);                                     \
    aSrc0 += 16; aSrc1 += 16;                                             \
    bSrc += 16 * NN;                                                      \
  } while (0)

  float acc[2][4][4] = {};           // [qj][i][j] = C[ty4+i][qj*32+tx4+j]

  // Per-tile compute: 16 k-steps. Per acc element the FMA order is
  // kq(0..3) -> h(0..1) -> d(0..1): k = kq*4+h*2+d strictly ascending —
  // bit-identical chain to v0. A held as 4 float2 halves (8 regs), B as
  // 2 float4 (8 regs): live set fits the 85-reg / 3-wave budget.
#define COMPUTE(q)                                                        \
  do {                                                                    \
    _Pragma("unroll") for (int kq = 0; kq < 4; ++kq) {                    \
      const int sc = ((kq ^ tyq) << 2);  /* stored col of global quad kq */\
      _Pragma("unroll") for (int h = 0; h < 2; ++h) {                     \
        float2 a0 = *(const float2*)&As[q][ty4 + 0][sc + h * 2];          \
        float2 a1 = *(const float2*)&As[q][ty4 + 1][sc + h * 2];          \
        float2 a2 = *(const float2*)&As[q][ty4 + 2][sc + h * 2];          \
        float2 a3 = *(const float2*)&As[q][ty4 + 3][sc + h * 2];          \
        _Pragma("unroll") for (int d = 0; d < 2; ++d) {                   \
          const int kk = kq * 4 + h * 2 + d;                              \
          float4 b0 = *(const float4*)&Bs[q][kk][tx4];                    \
          float4 b1 = *(const float4*)&Bs[q][kk][32 + tx4];               \
          _Pragma("unroll") for (int i = 0; i < 4; ++i) {                 \
            const float a = (d == 0)                                      \
                ? (i == 0 ? a0.x : i == 1 ? a1.x : i == 2 ? a2.x : a3.x)  \
                : (i == 0 ? a0.y : i == 1 ? a1.y : i == 2 ? a2.y : a3.y); \
            acc[0][i][0] = fmaf(a, b0.x, acc[0][i][0]);                   \
            acc[0][i][1] = fmaf(a, b0.y, acc[0][i][1]);                   \
            acc[0][i][2] = fmaf(a, b0.z, acc[0][i][2]);                   \
            acc[0][i][3] = fmaf(a, b0.w, acc[0][i][3]);                   \
            acc[1][i][0] = fmaf(a, b1.x, acc[1][i][0]);                   \
            acc[1][i][1] = fmaf(a, b1.y, acc[1][i][1]);                   \
            acc[1][i][2] = fmaf(a, b1.z, acc[1][i][2]);                   \
            acc[1][i][3] = fmaf(a, b1.w, acc[1][i][3]);                   \
          }                                                               \
        }                                                                 \
      }                                                                   \
    }                                                                     \
  } while (0)

  // prologue: tile 0 -> buf0 (one exposed DMA latency, once per kernel)
  ISSUE(0);
  __syncthreads();                    // vmcnt(0) drain + barrier: buf0 ready

  // 49 tiles = 24 pairs + epilogue. Invariant: entering pair p, buf0 holds
  // tile 2p (staged & visible).
  for (int p = 0; p < 24; ++p) {
    ISSUE(1);                         // tile 2p+1 -> buf1 (async DMA)
    COMPUTE(0);                       // tile 2p   (~1024 cyc of cover)
    __syncthreads();                  // buf1 ready; all waves done with buf0
    ISSUE(0);                         // tile 2p+2 -> buf0 (async DMA)
    COMPUTE(1);                       // tile 2p+1
    __syncthreads();                  // buf0 ready; all waves done with buf1
  }
  COMPUTE(0);                         // tile 48

#undef ISSUE
#undef COMPUTE

#pragma unroll
  for (int i = 0; i < 4; ++i) {
    const int r = m0 + ty4 + i;
    float4 v0 = {acc[0][i][0], acc[0][i][1], acc[0][i][2], acc[0][i][3]};
    float4 v1 = {acc[1][i][0], acc[1][i][1], acc[1][i][2], acc[1][i][3]};
    *(float4*)(C + (size_t)r * NN + n0 + tx4) = v0;
    *(float4*)(C + (size_t)r * NN + n0 + 32 + tx4) = v1;
  }
}

// ---------------- Phase 2: sequential scan, one block per batch row --------
// 1024 threads (1 neuron each, 16 waves). hid holds net on entry; overwritten
// in place with spikes. One lgkm-only barrier per step (inline asm) so the
// spike stores and depth-2 net prefetch stay in flight across the barrier.
// (UNCHANGED.)
__global__ __launch_bounds__(1024)
void snn_scan(float* __restrict__ hid, const float* __restrict__ Wout,
              float* __restrict__ logits) {
  constexpr float V_REST = -65.0f, THRESH0 = -50.0f, TAU_M = 20.0f,
                  TAU_TH = 100.0f, BETA = 5.0f, DT = 1.0f;
  const int b = blockIdx.x;
  const int tid = threadIdx.x;
  const int wave = tid >> 6, lane = tid & 63;
  __shared__ float s_part[2][16];
  __shared__ float s_log[16][OO];

  float mp = V_REST, th = THRESH0, prev = 0.0f, cnt = 0.0f;
  float S = 0.0f;
  const size_t base = (size_t)b * NN + tid;
  const size_t STEP = (size_t)BB * NN;

  // depth-2 prefetch pipeline for net
  float netc = hid[base];                 // t = 0
  float netn = hid[STEP + base];          // t = 1

  for (int t = 0; t < TT; ++t) {
    float rec = -0.5f * (S - prev);       // exact closed-form prev@W_rec
    float nv = netc + rec;                // matches np elementwise add order
    float m = mp + (V_REST - mp) / TAU_M; // true division, as reference
    m = m + nv * DT;
    bool spk = (m >= th);
    float s = spk ? 1.0f : 0.0f;
    th = (th + BETA * s) - ((th - THRESH0) / TAU_TH) * DT; // old th both terms
    mp = spk ? V_REST : m;
    cnt += s;
    prev = s;
    hid[(size_t)t * STEP + base] = s;

    // rotate prefetch: issue t+2 now (independent of this step's results)
    float netf = 0.0f;
    if (t + 2 < TT) netf = hid[(size_t)(t + 2) * STEP + base];
    netc = netn;
    netn = netf;

    // row spike count: ballot+popcount per wave; parity-buffered partials;
    // lgkm-only barrier (global loads/stores NOT drained).
    unsigned long long bal = __ballot(spk);
    if (lane == 0) s_part[t & 1][wave] = (float)__popcll(bal);
    __asm__ volatile("s_waitcnt lgkmcnt(0)\n\ts_barrier" ::: "memory");
    const float* sp = s_part[t & 1];
    float4 p0 = *(const float4*)(sp + 0);
    float4 p1 = *(const float4*)(sp + 4);
    float4 p2 = *(const float4*)(sp + 8);
    float4 p3 = *(const float4*)(sp + 12);
    S = ((p0.x + p0.y) + (p0.z + p0.w)) + ((p1.x + p1.y) + (p1.z + p1.w)) +
        ((p2.x + p2.y) + (p2.z + p2.w)) + ((p3.x + p3.y) + (p3.z + p3.w));
  }

  // logits[b,o] = sum_j cnt[b,j] * Wout[j,o]
  float lg[OO];
#pragma unroll
  for (int o = 0; o < OO; ++o) lg[o] = cnt * Wout[(size_t)tid * OO + o];
#pragma unroll
  for (int o = 0; o < OO; ++o) {
    float v = lg[o];
#pragma unroll
    for (int d = 32; d > 0; d >>= 1) v += __shfl_down(v, d, 64);
    if (lane == 0) s_log[wave][o] = v;
  }
  __syncthreads();
  if (tid < OO) {
    float v = 0.0f;
#pragma unroll
    for (int w = 0; w < 16; ++w) v += s_log[w][tid];
    logits[(size_t)b * OO + tid] = v;
  }
}

extern "C" void kernel_launch(void* const* d_in, const int* in_sizes, int n_in,
                              void* d_out, int out_size, void* d_ws,
                              size_t ws_size, hipStream_t stream) {
  const float* X    = (const float*)d_in[0];  // input_spikes [200][256][784]
  const float* Win  = (const float*)d_in[1];  // [784][1024]
  // d_in[2] = W_rec — unused (exact closed form)
  const float* Wout = (const float*)d_in[3];  // [1024][10]

  float* logits = (float*)d_out;              // [256][10]
  float* hid    = (float*)d_out + BB * OO;    // [200][256][1024]

  dim3 g1(NN / 64, TT * BB / 128);            // 16 x 400 blocks
  gemm_net<<<g1, 256, 0, stream>>>(X, Win, hid);
  snn_scan<<<BB, 1024, 0, stream>>>(hid, Wout, logits);
}

// Round 8
// 1235.665 us; speedup vs baseline: 3.0965x; 1.0559x over previous
//
#include <hip/hip_runtime.h>

// SNN: T=200, B=256, IN=784, N=1024, OUT=10
// W_rec = -0.5*(ones - I) => prev@W_rec = -0.5*(S_b - prev[b,j])  (exact in
// fp32). net_in[t] = x_t @ W_in is time-independent => one fp32 GEMM up
// front into d_out's hidden_spikes region, then an in-place spike scan.
//
// NUMERICS CONTRACT: dynamics are knife-edge (absmax 512 of 611 = one
// marginal spike-step flip vs BLAS summation order). The GEMM keeps a single
// ascending-k fmaf chain per output element — bit-identical across rounds.
// No MFMA/bf16, no split-K, no reassociation, true division in the scan.
// Block-wide spike count S is a sum of integer-valued floats (<=1024):
// exact in fp32 under ANY summation order, so the reduction tree is free
// to change shape.
//
// v8 conclusions from v0..v7 counters (the constraint pair):
//  - LDS ratio: 8x8 micro-tile (1.0 B/FMA) is required; 4x8 (1.5 B/FMA)
//    caps VALUBusy at ~58-68% (v5, v7: LDS-delivery-bound).
//  - VGPR: must stay <=~85 for ~3 waves/SIMD (law: waves/SIMD ~
//    floor(256/VGPR)); every DMA/dbuf variant that grew past it stalled
//    or spilled (v2,v3,v4,v6).
//  v0 (80 VGPR, 8x8, reg-prefetch live across compute, 2 syncthreads/tile)
//  satisfies BOTH and remains the measured GEMM optimum (950us, 75% busy).
//  v8 = v0 GEMM + XCD-co-located grid (same-X-panel blocks -> same XCD L2;
//  grid transposed so their linear IDs are congruent mod 8) + scan rebuilt
//  at 512thr x 2 neurons (8-wave barrier instead of 16).

#define TT 200
#define BB 256
#define KK 784
#define NN 1024
#define OO 10

// ---------------- Phase 1: net = X(51200x784) @ W(784x1024), fp32 ----------
// v0 kernel verbatim (measured: 950us, VALUBusy 75%, VGPR 80, no spill).
// Only change: m-block = blockIdx.x (400), n-block = blockIdx.y (8), so the
// 8 blocks sharing one 128-row X panel have linear IDs x, 400+x, ..., 2800+x
// — all congruent mod 8 -> same XCD (round-robin dispatch) -> X panel is
// fetched once into that XCD's L2 instead of 8 times across 8 XCDs.
__global__ __launch_bounds__(256)
void gemm_net(const float* __restrict__ X, const float* __restrict__ W,
              float* __restrict__ C) {
  __shared__ float As[16][128];   // [k][m] (A staged transposed)
  __shared__ float Bs[16][128];   // [k][n]
  float4 (*As4)[32] = (float4(*)[32])As;
  float4 (*Bs4)[32] = (float4(*)[32])Bs;

  const int tid = threadIdx.x;
  const int m0 = blockIdx.x * 128;     // 400 m-blocks (fast axis)
  const int n0 = blockIdx.y * 128;     // 8 n-blocks   (slow axis)
  const int tx = tid & 15;             // cols tx*4, 64+tx*4
  const int ty = tid >> 4;             // rows ty*4, 64+ty*4
  const int arow = tid >> 1;           // 0..127
  const int ak   = (tid & 1) * 8;      // 0 or 8
  const int brow = tid >> 5;           // 0..7 (and +8)
  const int bc   = (tid & 31) * 4;     // 0..124

  const float* ap = X + (size_t)(m0 + arow) * KK + ak;
  const float* bp = W + (size_t)brow * NN + n0 + bc;

  // preload tile 0 into registers (live across compute: 16 regs + 64 acc
  // = the measured 80-VGPR optimum)
  float4 a0 = *(const float4*)(ap);
  float4 a1 = *(const float4*)(ap + 4);
  float4 b0 = *(const float4*)(bp);
  float4 b1 = *(const float4*)(bp + 8 * NN);

  float acc[2][2][4][4] = {};

  for (int k0 = 0; k0 < KK; k0 += 16) {
    __syncthreads();                   // previous tile's LDS reads done
    As[ak + 0][arow] = a0.x;           // bank=arow%32, 2-way (free)
    As[ak + 1][arow] = a0.y;
    As[ak + 2][arow] = a0.z;
    As[ak + 3][arow] = a0.w;
    As[ak + 4][arow] = a1.x;
    As[ak + 5][arow] = a1.y;
    As[ak + 6][arow] = a1.z;
    As[ak + 7][arow] = a1.w;
    *(float4*)&Bs[brow][bc] = b0;      // lane-consecutive: conflict-free
    *(float4*)&Bs[brow + 8][bc] = b1;
    __syncthreads();

    // prefetch next tile (latency overlapped by the 1024 FMAs below)
    if (k0 + 16 < KK) {
      ap += 16;
      bp += 16 * NN;
      a0 = *(const float4*)(ap);
      a1 = *(const float4*)(ap + 4);
      b0 = *(const float4*)(bp);
      b1 = *(const float4*)(bp + 8 * NN);
    }

#pragma unroll
    for (int k = 0; k < 16; ++k) {
      float4 A0 = As4[k][ty];          // broadcast (free)
      float4 A1 = As4[k][16 + ty];
      float4 B0 = Bs4[k][tx];          // 2-way (free)
      float4 B1 = Bs4[k][16 + tx];
      float av[2][4] = {{A0.x, A0.y, A0.z, A0.w}, {A1.x, A1.y, A1.z, A1.w}};
      float bv[2][4] = {{B0.x, B0.y, B0.z, B0.w}, {B1.x, B1.y, B1.z, B1.w}};
#pragma unroll
      for (int qi = 0; qi < 2; ++qi)
#pragma unroll
        for (int qj = 0; qj < 2; ++qj)
#pragma unroll
          for (int i = 0; i < 4; ++i)
#pragma unroll
            for (int j = 0; j < 4; ++j)
              acc[qi][qj][i][j] =
                  fmaf(av[qi][i], bv[qj][j], acc[qi][qj][i][j]);
    }
  }
#pragma unroll
  for (int qi = 0; qi < 2; ++qi)
#pragma unroll
    for (int i = 0; i < 4; ++i) {
      const int r = m0 + qi * 64 + ty * 4 + i;
#pragma unroll
      for (int qj = 0; qj < 2; ++qj) {
        float4 v = {acc[qi][qj][i][0], acc[qi][qj][i][1],
                    acc[qi][qj][i][2], acc[qi][qj][i][3]};
        *(float4*)(C + (size_t)r * NN + n0 + qj * 64 + tx * 4) = v;
      }
    }
}

// ---------------- Phase 2: sequential scan, one block per batch row --------
// v8: 512 threads x 2 neurons (was 1024 x 1). Halves the barrier width
// (8 waves) and the S-reduction (8 partials, 2x ds_read_b128 + 7 adds vs
// 16/15). Each neuron's update chain is instruction-identical to before;
// S = sum of per-wave ballot popcounts = integers, exact in fp32 in any
// order -> dynamics bit-identical. One lgkm-only barrier per step; spike
// stores and the depth-2 net prefetch stay in flight across it.
__global__ __launch_bounds__(512)
void snn_scan(float* __restrict__ hid, const float* __restrict__ Wout,
              float* __restrict__ logits) {
  constexpr float V_REST = -65.0f, THRESH0 = -50.0f, TAU_M = 20.0f,
                  TAU_TH = 100.0f, BETA = 5.0f, DT = 1.0f;
  const int b = blockIdx.x;
  const int tid = threadIdx.x;               // 0..511
  const int wave = tid >> 6, lane = tid & 63;  // 8 waves
  __shared__ float s_part[2][8];
  __shared__ float s_log[8][OO];

  float mpA = V_REST, thA = THRESH0, prevA = 0.0f, cntA = 0.0f;
  float mpB = V_REST, thB = THRESH0, prevB = 0.0f, cntB = 0.0f;
  float S = 0.0f;
  const size_t baseA = (size_t)b * NN + tid;       // neuron j = tid
  const size_t baseB = baseA + 512;                // neuron j = tid+512
  const size_t STEP = (size_t)BB * NN;

  // depth-2 prefetch pipeline for net (both neurons)
  float cA = hid[baseA], cB = hid[baseB];              // t = 0
  float nA = hid[STEP + baseA], nB = hid[STEP + baseB];  // t = 1

  for (int t = 0; t < TT; ++t) {
    // ---- neuron A (chain identical to the 1024-thread version) ----
    float recA = -0.5f * (S - prevA);
    float nvA = cA + recA;
    float mA = mpA + (V_REST - mpA) / TAU_M;
    mA = mA + nvA * DT;
    bool sA = (mA >= thA);
    float fA = sA ? 1.0f : 0.0f;
    thA = (thA + BETA * fA) - ((thA - THRESH0) / TAU_TH) * DT;
    mpA = sA ? V_REST : mA;
    cntA += fA;
    prevA = fA;
    // ---- neuron B ----
    float recB = -0.5f * (S - prevB);
    float nvB = cB + recB;
    float mB = mpB + (V_REST - mpB) / TAU_M;
    mB = mB + nvB * DT;
    bool sB = (mB >= thB);
    float fB = sB ? 1.0f : 0.0f;
    thB = (thB + BETA * fB) - ((thB - THRESH0) / TAU_TH) * DT;
    mpB = sB ? V_REST : mB;
    cntB += fB;
    prevB = fB;

    hid[(size_t)t * STEP + baseA] = fA;
    hid[(size_t)t * STEP + baseB] = fB;

    // rotate prefetch: issue t+2 now (independent of this step's results)
    float fAn = 0.0f, fBn = 0.0f;
    if (t + 2 < TT) {
      fAn = hid[(size_t)(t + 2) * STEP + baseA];
      fBn = hid[(size_t)(t + 2) * STEP + baseB];
    }
    cA = nA; nA = fAn;
    cB = nB; nB = fBn;

    // row spike count: 2 ballots per wave; integer-valued partials (exact);
    // parity-buffered; lgkm-only barrier (global ops NOT drained).
    unsigned long long balA = __ballot(sA);
    unsigned long long balB = __ballot(sB);
    if (lane == 0)
      s_part[t & 1][wave] = (float)(__popcll(balA) + __popcll(balB));
    __asm__ volatile("s_waitcnt lgkmcnt(0)\n\ts_barrier" ::: "memory");
    const float* sp = s_part[t & 1];
    float4 p0 = *(const float4*)(sp + 0);
    float4 p1 = *(const float4*)(sp + 4);
    S = ((p0.x + p0.y) + (p0.z + p0.w)) + ((p1.x + p1.y) + (p1.z + p1.w));
  }

  // logits[b,o] = sum_j cnt[b,j] * Wout[j,o]  (reduction order change is
  // ~1e-3 on O(1e4) logits; no feedback into dynamics)
  float lg[OO];
#pragma unroll
  for (int o = 0; o < OO; ++o)
    lg[o] = cntA * Wout[(size_t)tid * OO + o] +
            cntB * Wout[(size_t)(tid + 512) * OO + o];
#pragma unroll
  for (int o = 0; o < OO; ++o) {
    float v = lg[o];
#pragma unroll
    for (int d = 32; d > 0; d >>= 1) v += __shfl_down(v, d, 64);
    if (lane == 0) s_log[wave][o] = v;
  }
  __syncthreads();
  if (tid < OO) {
    float v = 0.0f;
#pragma unroll
    for (int w = 0; w < 8; ++w) v += s_log[w][tid];
    logits[(size_t)b * OO + tid] = v;
  }
}

extern "C" void kernel_launch(void* const* d_in, const int* in_sizes, int n_in,
                              void* d_out, int out_size, void* d_ws,
                              size_t ws_size, hipStream_t stream) {
  const float* X    = (const float*)d_in[0];  // input_spikes [200][256][784]
  const float* Win  = (const float*)d_in[1];  // [784][1024]
  // d_in[2] = W_rec — unused (exact closed form)
  const float* Wout = (const float*)d_in[3];  // [1024][10]

  float* logits = (float*)d_out;              // [256][10]
  float* hid    = (float*)d_out + BB * OO;    // [200][256][1024]

  dim3 g1(TT * BB / 128, NN / 128);           // 400 x 8 (m fast -> XCD co-loc)
  gemm_net<<<g1, 256, 0, stream>>>(X, Win, hid);
  snn_scan<<<BB, 512, 0, stream>>>(hid, Wout, logits);
}

// Round 9
// 1183.972 us; speedup vs baseline: 3.2317x; 1.0437x over previous
//
#include <hip/hip_runtime.h>

// SNN: T=200, B=256, IN=784, N=1024, OUT=10
// W_rec = -0.5*(ones - I) => prev@W_rec = -0.5*(S_b - prev[b,j])  (exact in
// fp32). net_in[t] = x_t @ W_in is time-independent => one fp32 GEMM up
// front into d_out's hidden_spikes region, then an in-place spike scan.
//
// NUMERICS CONTRACT: dynamics are knife-edge (absmax 512 of 611 = one
// marginal spike-step flip vs BLAS summation order). The GEMM keeps a single
// ascending-k fmaf chain per output element — bit-identical across rounds.
// No MFMA/bf16, no split-K, no reassociation, true division in the scan.
// Block-wide spike count S is a sum of integer-valued floats (<=1024):
// exact in fp32 under ANY summation order -> reduction tree shape is free.
//
// v9 state of knowledge (all counters-measured):
//  GEMM: v0 structure (80 VGPR, 8x8 micro, reg-prefetch, 2 syncthreads/tile)
//  is the probed optimum — every deviation (reg-dbuf v2/v3: spills; DMA
//  v4/v6: VGPR>128 -> 1-2 waves/SIMD; 4x8 v5/v7: 1.5 B/FMA LDS wall) lost.
//  With the m-fast grid (v8): 912us, VALUBusy 76%. GEMM untouched.
//  SCAN: v8's 512thr x 2-neuron scan = ~324us vs ~70us memory floor. The
//  "depth-2 prefetch" rotation (netc=netn; netn=netf) copies the load's
//  DEST REGISTER -> forces s_waitcnt vmcnt in the SAME step the load
//  issues -> every one of 200 serial steps eats an exposed global latency.
//  v9: unroll time by 4 with 4 NAMED prefetch regs per neuron (no rotation
//  movs); load issued at step t is first read at step t+4 (~4x300 cyc of
//  cover) -> the per-step exposed latency collapses to the VALU+barrier
//  chain. Arithmetic chain per step unchanged -> bit-identical.

#define TT 200
#define BB 256
#define KK 784
#define NN 1024
#define OO 10

// ---------------- Phase 1: net = X(51200x784) @ W(784x1024), fp32 ----------
// v0 kernel verbatim; m-block on blockIdx.x (fast axis) as in v8 (912us).
__global__ __launch_bounds__(256)
void gemm_net(const float* __restrict__ X, const float* __restrict__ W,
              float* __restrict__ C) {
  __shared__ float As[16][128];   // [k][m] (A staged transposed)
  __shared__ float Bs[16][128];   // [k][n]
  float4 (*As4)[32] = (float4(*)[32])As;
  float4 (*Bs4)[32] = (float4(*)[32])Bs;

  const int tid = threadIdx.x;
  const int m0 = blockIdx.x * 128;     // 400 m-blocks (fast axis)
  const int n0 = blockIdx.y * 128;     // 8 n-blocks   (slow axis)
  const int tx = tid & 15;             // cols tx*4, 64+tx*4
  const int ty = tid >> 4;             // rows ty*4, 64+ty*4
  const int arow = tid >> 1;           // 0..127
  const int ak   = (tid & 1) * 8;      // 0 or 8
  const int brow = tid >> 5;           // 0..7 (and +8)
  const int bc   = (tid & 31) * 4;     // 0..124

  const float* ap = X + (size_t)(m0 + arow) * KK + ak;
  const float* bp = W + (size_t)brow * NN + n0 + bc;

  // preload tile 0 into registers (live across compute: 16 regs + 64 acc
  // = the measured 80-VGPR optimum)
  float4 a0 = *(const float4*)(ap);
  float4 a1 = *(const float4*)(ap + 4);
  float4 b0 = *(const float4*)(bp);
  float4 b1 = *(const float4*)(bp + 8 * NN);

  float acc[2][2][4][4] = {};

  for (int k0 = 0; k0 < KK; k0 += 16) {
    __syncthreads();                   // previous tile's LDS reads done
    As[ak + 0][arow] = a0.x;           // bank=arow%32, 2-way (free)
    As[ak + 1][arow] = a0.y;
    As[ak + 2][arow] = a0.z;
    As[ak + 3][arow] = a0.w;
    As[ak + 4][arow] = a1.x;
    As[ak + 5][arow] = a1.y;
    As[ak + 6][arow] = a1.z;
    As[ak + 7][arow] = a1.w;
    *(float4*)&Bs[brow][bc] = b0;      // lane-consecutive: conflict-free
    *(float4*)&Bs[brow + 8][bc] = b1;
    __syncthreads();

    // prefetch next tile (latency overlapped by the 1024 FMAs below)
    if (k0 + 16 < KK) {
      ap += 16;
      bp += 16 * NN;
      a0 = *(const float4*)(ap);
      a1 = *(const float4*)(ap + 4);
      b0 = *(const float4*)(bp);
      b1 = *(const float4*)(bp + 8 * NN);
    }

#pragma unroll
    for (int k = 0; k < 16; ++k) {
      float4 A0 = As4[k][ty];          // broadcast (free)
      float4 A1 = As4[k][16 + ty];
      float4 B0 = Bs4[k][tx];          // 2-way (free)
      float4 B1 = Bs4[k][16 + tx];
      float av[2][4] = {{A0.x, A0.y, A0.z, A0.w}, {A1.x, A1.y, A1.z, A1.w}};
      float bv[2][4] = {{B0.x, B0.y, B0.z, B0.w}, {B1.x, B1.y, B1.z, B1.w}};
#pragma unroll
      for (int qi = 0; qi < 2; ++qi)
#pragma unroll
        for (int qj = 0; qj < 2; ++qj)
#pragma unroll
          for (int i = 0; i < 4; ++i)
#pragma unroll
            for (int j = 0; j < 4; ++j)
              acc[qi][qj][i][j] =
                  fmaf(av[qi][i], bv[qj][j], acc[qi][qj][i][j]);
    }
  }
#pragma unroll
  for (int qi = 0; qi < 2; ++qi)
#pragma unroll
    for (int i = 0; i < 4; ++i) {
      const int r = m0 + qi * 64 + ty * 4 + i;
#pragma unroll
      for (int qj = 0; qj < 2; ++qj) {
        float4 v = {acc[qi][qj][i][0], acc[qi][qj][i][1],
                    acc[qi][qj][i][2], acc[qi][qj][i][3]};
        *(float4*)(C + (size_t)r * NN + n0 + qj * 64 + tx * 4) = v;
      }
    }
}

// ---------------- Phase 2: sequential scan, one block per batch row --------
// 512 threads x 2 neurons, 8 waves. v9: time loop unrolled by 4 with 4
// NAMED prefetch registers per neuron — the load issued at step t is first
// read at step t+4, so its s_waitcnt lands 4 step-bodies later instead of
// in the issuing step (v8's rotation movs forced a same-step wait). One
// lgkm-only barrier per step (global loads/stores NOT drained).
__global__ __launch_bounds__(512)
void snn_scan(float* __restrict__ hid, const float* __restrict__ Wout,
              float* __restrict__ logits) {
  constexpr float V_REST = -65.0f, THRESH0 = -50.0f, TAU_M = 20.0f,
                  TAU_TH = 100.0f, BETA = 5.0f, DT = 1.0f;
  const int b = blockIdx.x;
  const int tid = threadIdx.x;                 // 0..511
  const int wave = tid >> 6, lane = tid & 63;  // 8 waves
  __shared__ float s_part[2][8];
  __shared__ float s_log[8][OO];

  float mpA = V_REST, thA = THRESH0, prevA = 0.0f, cntA = 0.0f;
  float mpB = V_REST, thB = THRESH0, prevB = 0.0f, cntB = 0.0f;
  float S = 0.0f;
  const size_t baseA = (size_t)b * NN + tid;   // neuron j = tid
  const size_t baseB = baseA + 512;            // neuron j = tid+512
  const size_t STEP = (size_t)BB * NN;

  // depth-4 prefetch: 4 named regs per neuron, NO rotation movs.
  float pA0 = hid[baseA],             pB0 = hid[baseB];
  float pA1 = hid[STEP + baseA],      pB1 = hid[STEP + baseB];
  float pA2 = hid[2 * STEP + baseA],  pB2 = hid[2 * STEP + baseB];
  float pA3 = hid[3 * STEP + baseA],  pB3 = hid[3 * STEP + baseB];

  // One time-step. Consumes (nA_, nB_) = net values for step t, then
  // re-issues them as prefetch for step t+4. Arithmetic chain identical
  // to v8 (and to the original 1024-thread scan) -> bit-identical.
#define SCAN_STEP(t, nA_, nB_)                                             \
  do {                                                                     \
    float recA = -0.5f * (S - prevA);                                      \
    float nvA = (nA_) + recA;                                              \
    float mA = mpA + (V_REST - mpA) / TAU_M;                               \
    mA = mA + nvA * DT;                                                    \
    bool sA = (mA >= thA);                                                 \
    float fA = sA ? 1.0f : 0.0f;                                           \
    thA = (thA + BETA * fA) - ((thA - THRESH0) / TAU_TH) * DT;             \
    mpA = sA ? V_REST : mA;                                                \
    cntA += fA;                                                            \
    prevA = fA;                                                            \
    float recB = -0.5f * (S - prevB);                                      \
    float nvB = (nB_) + recB;                                              \
    float mB = mpB + (V_REST - mpB) / TAU_M;                               \
    mB = mB + nvB * DT;                                                    \
    bool sB = (mB >= thB);                                                 \
    float fB = sB ? 1.0f : 0.0f;                                           \
    thB = (thB + BETA * fB) - ((thB - THRESH0) / TAU_TH) * DT;             \
    mpB = sB ? V_REST : mB;                                                \
    cntB += fB;                                                            \
    prevB = fB;                                                            \
    hid[(size_t)(t) * STEP + baseA] = fA;                                  \
    hid[(size_t)(t) * STEP + baseB] = fB;                                  \
    if ((t) + 4 < TT) {                                                    \
      nA_ = hid[(size_t)((t) + 4) * STEP + baseA];                         \
      nB_ = hid[(size_t)((t) + 4) * STEP + baseB];                         \
    }                                                                      \
    unsigned long long balA = __ballot(sA);                                \
    unsigned long long balB = __ballot(sB);                                \
    if (lane == 0)                                                         \
      s_part[(t) & 1][wave] = (float)(__popcll(balA) + __popcll(balB));    \
    __asm__ volatile("s_waitcnt lgkmcnt(0)\n\ts_barrier" ::: "memory");    \
    const float* sp = s_part[(t) & 1];                                     \
    float4 q0 = *(const float4*)(sp + 0);                                  \
    float4 q1 = *(const float4*)(sp + 4);                                  \
    S = ((q0.x + q0.y) + (q0.z + q0.w)) + ((q1.x + q1.y) + (q1.z + q1.w)); \
  } while (0)

  for (int t = 0; t < TT; t += 4) {   // TT=200: 50 iterations, no tail
    SCAN_STEP(t + 0, pA0, pB0);
    SCAN_STEP(t + 1, pA1, pB1);
    SCAN_STEP(t + 2, pA2, pB2);
    SCAN_STEP(t + 3, pA3, pB3);
  }
#undef SCAN_STEP

  // logits[b,o] = sum_j cnt[b,j] * Wout[j,o]  (reduction order change is
  // ~1e-3 on O(1e4) logits; no feedback into dynamics)
  float lg[OO];
#pragma unroll
  for (int o = 0; o < OO; ++o)
    lg[o] = cntA * Wout[(size_t)tid * OO + o] +
            cntB * Wout[(size_t)(tid + 512) * OO + o];
#pragma unroll
  for (int o = 0; o < OO; ++o) {
    float v = lg[o];
#pragma unroll
    for (int d = 32; d > 0; d >>= 1) v += __shfl_down(v, d, 64);
    if (lane == 0) s_log[wave][o] = v;
  }
  __syncthreads();
  if (tid < OO) {
    float v = 0.0f;
#pragma unroll
    for (int w = 0; w < 8; ++w) v += s_log[w][tid];
    logits[(size_t)b * OO + tid] = v;
  }
}

extern "C" void kernel_launch(void* const* d_in, const int* in_sizes, int n_in,
                              void* d_out, int out_size, void* d_ws,
                              size_t ws_size, hipStream_t stream) {
  const float* X    = (const float*)d_in[0];  // input_spikes [200][256][784]
  const float* Win  = (const float*)d_in[1];  // [784][1024]
  // d_in[2] = W_rec — unused (exact closed form)
  const float* Wout = (const float*)d_in[3];  // [1024][10]

  float* logits = (float*)d_out;              // [256][10]
  float* hid    = (float*)d_out + BB * OO;    // [200][256][1024]

  dim3 g1(TT * BB / 128, NN / 128);           // 400 x 8 (m fast)
  gemm_net<<<g1, 256, 0, stream>>>(X, Win, hid);
  snn_scan<<<BB, 512, 0, stream>>>(hid, Wout, logits);
}